// Round 1
// baseline (312.833 us; speedup 1.0000x reference)
//
#include <hip/hip_runtime.h>
#include <hip/hip_bf16.h>

#define LEN   2048
#define KNB   32
#define NFEAT 416   // 16 pos + 25*16 rbf
#define HID   128

// ---------------------------------------------------------------------------
// Kernel 1: top-K neighbor selection per residue.
// One block (256 threads) per (b,i). dist_sq computed with explicit rn ops to
// bit-match the numpy reference ((dx*dx + dy*dy) + dz*dz), tie-break by index
// via packed (float_bits<<32 | j) keys -> matches lax.top_k stable ordering.
// ---------------------------------------------------------------------------

__device__ __forceinline__ unsigned long long shfl_xor_u64(unsigned long long v, int m) {
    unsigned int lo = (unsigned int)(v & 0xFFFFFFFFull);
    unsigned int hi = (unsigned int)(v >> 32);
    lo = __shfl_xor(lo, m, 64);
    hi = __shfl_xor(hi, m, 64);
    return (((unsigned long long)hi) << 32) | (unsigned long long)lo;
}

__global__ __launch_bounds__(256) void topk_kernel(
    const float* __restrict__ X, const float* __restrict__ mask,
    float* __restrict__ eidx_out) {
    const int row = blockIdx.x;              // b*LEN + i
    const int b = row >> 11;
    const int i = row & (LEN - 1);

    __shared__ unsigned long long keys[LEN];
    __shared__ unsigned long long warr[4];

    const float* Xb = X + (size_t)b * LEN * 12;
    const float cax = Xb[i * 12 + 3];
    const float cay = Xb[i * 12 + 4];
    const float caz = Xb[i * 12 + 5];
    const float* mb = mask + (size_t)b * LEN;

    for (int j = threadIdx.x; j < LEN; j += 256) {
        float dx = __fsub_rn(cax, Xb[j * 12 + 3]);
        float dy = __fsub_rn(cay, Xb[j * 12 + 4]);
        float dz = __fsub_rn(caz, Xb[j * 12 + 5]);
        float d2 = __fadd_rn(__fadd_rn(__fmul_rn(dx, dx), __fmul_rn(dy, dy)),
                             __fmul_rn(dz, dz));
        d2 = __fadd_rn(d2, __fmul_rn(__fsub_rn(1.0f, mb[j]), 1000000.0f));
        keys[j] = (((unsigned long long)__float_as_uint(d2)) << 32) | (unsigned int)j;
    }
    __syncthreads();

    // per-thread cached min over its 8 strided slots
    unsigned long long lmin = ~0ull;
#pragma unroll
    for (int q = 0; q < LEN / 256; ++q) {
        unsigned long long kk = keys[threadIdx.x + q * 256];
        lmin = kk < lmin ? kk : lmin;
    }

    for (int k = 0; k < KNB; ++k) {
        unsigned long long r = lmin;
#pragma unroll
        for (int off = 32; off >= 1; off >>= 1) {
            unsigned long long o = shfl_xor_u64(r, off);
            r = o < r ? o : r;
        }
        if ((threadIdx.x & 63) == 0) warr[threadIdx.x >> 6] = r;
        __syncthreads();
        unsigned long long g01 = warr[0] < warr[1] ? warr[0] : warr[1];
        unsigned long long g23 = warr[2] < warr[3] ? warr[2] : warr[3];
        unsigned long long g = g01 < g23 ? g01 : g23;
        const int win = (int)(unsigned int)(g & 0xFFFFFFFFull);
        if (threadIdx.x == 0) {
            eidx_out[(size_t)row * KNB + k] = (float)win;  // exact for idx < 2^24
            keys[win] = ~0ull;
        }
        __syncthreads();
        if (threadIdx.x == (win & 255)) {   // owner rescans its slots
            lmin = ~0ull;
#pragma unroll
            for (int q = 0; q < LEN / 256; ++q) {
                unsigned long long kk = keys[threadIdx.x + q * 256];
                lmin = kk < lmin ? kk : lmin;
            }
        }
    }
}

// ---------------------------------------------------------------------------
// Kernel 2: fused edge features + (32x416)x(416x128) matvec + LayerNorm.
// One block (256 threads) per (b,i): the row's 32 edges share the W_edge
// panel. featT[416][32] in LDS (transposed for conflict-free b128 reads),
// W_edge chunk-staged 16 features at a time ([16][132] padded), each thread
// accumulates a 4-edge x 4-output register tile.
// ---------------------------------------------------------------------------

__device__ __forceinline__ void load_res_atoms(const float* __restrict__ p, float* dst) {
    const float Nx = p[0], Ny = p[1], Nz = p[2];
    const float Ax = p[3], Ay = p[4], Az = p[5];
    const float Cx = p[6], Cy = p[7], Cz = p[8];
    const float Ox = p[9], Oy = p[10], Oz = p[11];
    const float bx = Ax - Nx, by = Ay - Ny, bz = Az - Nz;
    const float cx = Cx - Ax, cy = Cy - Ay, cz = Cz - Az;
    const float axv = by * cz - bz * cy;
    const float ayv = bz * cx - bx * cz;
    const float azv = bx * cy - by * cx;
    const float CBx = -0.58273431f * axv + 0.56802827f * bx + -0.54067466f * cx + Ax;
    const float CBy = -0.58273431f * ayv + 0.56802827f * by + -0.54067466f * cy + Ay;
    const float CBz = -0.58273431f * azv + 0.56802827f * bz + -0.54067466f * cz + Az;
    dst[0] = Nx;  dst[1] = Ny;  dst[2] = Nz;
    dst[3] = Ax;  dst[4] = Ay;  dst[5] = Az;
    dst[6] = Cx;  dst[7] = Cy;  dst[8] = Cz;
    dst[9] = Ox;  dst[10] = Oy; dst[11] = Oz;
    dst[12] = CBx; dst[13] = CBy; dst[14] = CBz;
}

__global__ __launch_bounds__(256) void edge_kernel(
    const float* __restrict__ X,
    const int* __restrict__ Ridx, const int* __restrict__ Chain,
    const float* __restrict__ W_pos, const float* __restrict__ b_pos,
    const float* __restrict__ W_edge,
    const float* __restrict__ lng, const float* __restrict__ lnb,
    const float* __restrict__ eidx_f, float* __restrict__ outE) {
    const int row = blockIdx.x;
    const int b = row >> 11;
    const int i = row & (LEN - 1);
    const int tid = threadIdx.x;

    __shared__ float featT[NFEAT * 32];     // [f][e]; reused as hbuf[32][132] after GEMM
    __shared__ float wlds[16 * 132];        // [f_sub][t] padded 128->132
    __shared__ float natoms[32 * 16];       // neighbor atoms (5 atoms x 3, padded)
    __shared__ float iatoms[16];            // center atoms
    __shared__ int jidx[KNB];

    const float* Xb = X + (size_t)b * LEN * 12;

    if (tid < KNB) {
        const int j = (int)eidx_f[(size_t)row * KNB + tid];
        jidx[tid] = j;
        load_res_atoms(Xb + j * 12, natoms + tid * 16);
    } else if (tid == KNB) {
        load_res_atoms(Xb + i * 12, iatoms);
    }
    __syncthreads();

    // --- positional encoding features: feat[p][e] = W_pos[p][d_final] + b_pos[p]
    const int Ri = Ridx[b * LEN + i];
    const int Ci = Chain[b * LEN + i];
#pragma unroll
    for (int it = 0; it < 2; ++it) {
        const int task = tid + it * 256;            // 512 tasks = 32 e x 16 p
        const int e = task >> 4, p = task & 15;
        const int j = jidx[e];
        const int drel = Ridx[b * LEN + j] - Ri;
        const int same = (Chain[b * LEN + j] == Ci);
        int dc = drel + 32;
        dc = dc < 0 ? 0 : (dc > 64 ? 64 : dc);
        const int df = same ? dc : 65;
        featT[p * 32 + e] = W_pos[p * 66 + df] + b_pos[p];
    }

    // --- RBF features: 800 tasks = 25 (m,n) pairs x 32 edges, 16 rbf each
    for (int task = tid; task < 800; task += 256) {
        const int mn = task >> 5, e = task & 31;
        const int m = mn / 5, n = mn - m * 5;
        const float ax = iatoms[m * 3 + 0];
        const float ay = iatoms[m * 3 + 1];
        const float az = iatoms[m * 3 + 2];
        const float* na = natoms + e * 16 + n * 3;
        const float dx = ax - na[0], dy = ay - na[1], dz = az - na[2];
        const float D = sqrtf(dx * dx + dy * dy + dz * dz + 1e-6f);
#pragma unroll
        for (int r = 0; r < 16; ++r) {
            const float mu = (float)(2.0 + (double)r * (20.0 / 15.0));  // np.linspace match
            const float t = D - mu;
            featT[(16 + mn * 16 + r) * 32 + e] = __expf(-(t * t) * (1.0f / 1.5625f));
        }
    }
    __syncthreads();

    // --- GEMM: h[e][t] = sum_f featT[f][e] * W_edge[t][f]
    const int tt = tid & 31;   // output group: t = tt*4 .. +3
    const int te = tid >> 5;   // edge group:  e = te*4 .. +3
    float acc[4][4] = {};

    for (int ch = 0; ch < 26; ++ch) {
        const int fc = ch * 16;
        // stage W chunk: 128 rows x 16 cols, transposed into wlds[f][t]
#pragma unroll
        for (int qq = 0; qq < 2; ++qq) {
            const int q = tid + qq * 256;          // 512 float4 loads
            const int rrow = q >> 2, c4 = q & 3;
            const float4 w = *(const float4*)(W_edge + rrow * 416 + fc + c4 * 4);
            wlds[(c4 * 4 + 0) * 132 + rrow] = w.x;
            wlds[(c4 * 4 + 1) * 132 + rrow] = w.y;
            wlds[(c4 * 4 + 2) * 132 + rrow] = w.z;
            wlds[(c4 * 4 + 3) * 132 + rrow] = w.w;
        }
        __syncthreads();
#pragma unroll
        for (int f = 0; f < 16; ++f) {
            const float4 a = *(const float4*)(featT + (fc + f) * 32 + te * 4);
            const float4 w = *(const float4*)(wlds + f * 132 + tt * 4);
            acc[0][0] = fmaf(a.x, w.x, acc[0][0]);
            acc[0][1] = fmaf(a.x, w.y, acc[0][1]);
            acc[0][2] = fmaf(a.x, w.z, acc[0][2]);
            acc[0][3] = fmaf(a.x, w.w, acc[0][3]);
            acc[1][0] = fmaf(a.y, w.x, acc[1][0]);
            acc[1][1] = fmaf(a.y, w.y, acc[1][1]);
            acc[1][2] = fmaf(a.y, w.z, acc[1][2]);
            acc[1][3] = fmaf(a.y, w.w, acc[1][3]);
            acc[2][0] = fmaf(a.z, w.x, acc[2][0]);
            acc[2][1] = fmaf(a.z, w.y, acc[2][1]);
            acc[2][2] = fmaf(a.z, w.z, acc[2][2]);
            acc[2][3] = fmaf(a.z, w.w, acc[2][3]);
            acc[3][0] = fmaf(a.w, w.x, acc[3][0]);
            acc[3][1] = fmaf(a.w, w.y, acc[3][1]);
            acc[3][2] = fmaf(a.w, w.z, acc[3][2]);
            acc[3][3] = fmaf(a.w, w.w, acc[3][3]);
        }
        __syncthreads();
    }

    // --- scatter h to LDS (reuse featT region, stride 132 to spread banks)
    float* hbuf = featT;
#pragma unroll
    for (int ee = 0; ee < 4; ++ee) {
        float4 h4;
        h4.x = acc[ee][0]; h4.y = acc[ee][1]; h4.z = acc[ee][2]; h4.w = acc[ee][3];
        *(float4*)(hbuf + (te * 4 + ee) * 132 + tt * 4) = h4;
    }
    __syncthreads();

    // --- LayerNorm: 8 threads per edge, 16 values each
    const int g = tid >> 3;     // edge
    const int l = tid & 7;      // sub-lane
    const float4* hb4 = (const float4*)(hbuf + g * 132 + l * 16);
    float4 vv[4];
    float s = 0.0f, ssq = 0.0f;
#pragma unroll
    for (int u = 0; u < 4; ++u) {
        vv[u] = hb4[u];
        s += vv[u].x + vv[u].y + vv[u].z + vv[u].w;
        ssq += vv[u].x * vv[u].x + vv[u].y * vv[u].y + vv[u].z * vv[u].z + vv[u].w * vv[u].w;
    }
#pragma unroll
    for (int off = 1; off < 8; off <<= 1) {
        s += __shfl_xor(s, off, 64);
        ssq += __shfl_xor(ssq, off, 64);
    }
    const float mean = s * (1.0f / 128.0f);
    float var = ssq * (1.0f / 128.0f) - mean * mean;
    const float rstd = rsqrtf(var + 1e-5f);

    float4* ob = (float4*)(outE + ((size_t)row * KNB + g) * HID + l * 16);
    const float4* g4 = (const float4*)(lng + l * 16);
    const float4* b4 = (const float4*)(lnb + l * 16);
#pragma unroll
    for (int u = 0; u < 4; ++u) {
        const float4 gg = g4[u];
        const float4 bb = b4[u];
        float4 o;
        o.x = (vv[u].x - mean) * rstd * gg.x + bb.x;
        o.y = (vv[u].y - mean) * rstd * gg.y + bb.y;
        o.z = (vv[u].z - mean) * rstd * gg.z + bb.z;
        o.w = (vv[u].w - mean) * rstd * gg.w + bb.w;
        ob[u] = o;
    }
}

extern "C" void kernel_launch(void* const* d_in, const int* in_sizes, int n_in,
                              void* d_out, int out_size, void* d_ws, size_t ws_size,
                              hipStream_t stream) {
    const float* X      = (const float*)d_in[0];
    const float* mask   = (const float*)d_in[1];
    const int*   Ridx   = (const int*)d_in[2];
    const int*   Chain  = (const int*)d_in[3];
    const float* W_pos  = (const float*)d_in[4];
    const float* b_pos  = (const float*)d_in[5];
    const float* W_edge = (const float*)d_in[6];
    const float* lng    = (const float*)d_in[7];
    const float* lnb    = (const float*)d_in[8];

    float* out   = (float*)d_out;
    float* eidx  = out;                          // B*L*K floats (exact ints)
    float* E     = out + (size_t)2 * LEN * KNB;  // B*L*K*HID floats

    const int nrow = 2 * LEN;
    topk_kernel<<<nrow, 256, 0, stream>>>(X, mask, eidx);
    edge_kernel<<<nrow, 256, 0, stream>>>(X, Ridx, Chain, W_pos, b_pos, W_edge,
                                          lng, lnb, eidx, E);
}

// Round 2
// 187.364 us; speedup vs baseline: 1.6697x; 1.6697x over previous
//
#include <hip/hip_runtime.h>
#include <hip/hip_bf16.h>

#define LEN   2048
#define KNB   32
#define HID   128

typedef unsigned long long ull;
typedef __bf16 bf16x8 __attribute__((ext_vector_type(8)));
typedef float  f32x4  __attribute__((ext_vector_type(4)));

// ---------------------------------------------------------------------------
// Kernel 0: prep — pack CA coords + mask penalty as float4, convert W to bf16.
// Grid: 208 blocks x 256 = 53248 threads == 128*416.
// ---------------------------------------------------------------------------
__global__ __launch_bounds__(256) void prep_kernel(
    const float* __restrict__ X, const float* __restrict__ mask,
    const float* __restrict__ W_edge,
    float4* __restrict__ CAm, __bf16* __restrict__ Wbf) {
    const int t = blockIdx.x * 256 + threadIdx.x;
    if (t < 2 * LEN) {
        const float* p = X + (size_t)t * 12;
        // identical op sequence to the old in-kernel penalty -> bit-identical keys
        CAm[t] = make_float4(p[3], p[4], p[5],
                             __fmul_rn(__fsub_rn(1.0f, mask[t]), 1000000.0f));
    }
    Wbf[t] = (__bf16)W_edge[t];
}

// ---------------------------------------------------------------------------
// Kernel 1: top-K=32 selection. Phase 1: 256 threads build u64 keys
// (f32bits<<32 | j) from packed CAm (coalesced float4). Phase 2: wave 0 only —
// per-lane top-3 cache over its 32 slots, 64-lane butterfly argmin per round,
// rescan only when a lane's cache is exhausted. Exact (unique keys).
// ---------------------------------------------------------------------------
__device__ __forceinline__ ull shfl_xor_u64(ull v, int m) {
    unsigned int lo = (unsigned int)(v & 0xFFFFFFFFull);
    unsigned int hi = (unsigned int)(v >> 32);
    lo = __shfl_xor(lo, m, 64);
    hi = __shfl_xor(hi, m, 64);
    return (((ull)hi) << 32) | (ull)lo;
}

__device__ __forceinline__ void ins3(ull k, ull& m1, ull& m2, ull& m3) {
    if (k < m3) {
        if (k < m2) {
            if (k < m1) { m3 = m2; m2 = m1; m1 = k; }
            else        { m3 = m2; m2 = k; }
        } else m3 = k;
    }
}

__global__ __launch_bounds__(256) void topk_kernel(
    const float4* __restrict__ CAm, float* __restrict__ eidx_out) {
    const int row = blockIdx.x;
    const int b = row >> 11;
    const int i = row & (LEN - 1);

    __shared__ ull keys[LEN];
    const float4* C = CAm + (size_t)b * LEN;
    const float4 ci = C[i];

    for (int j = threadIdx.x; j < LEN; j += 256) {
        const float4 cj = C[j];
        float dx = __fsub_rn(ci.x, cj.x);
        float dy = __fsub_rn(ci.y, cj.y);
        float dz = __fsub_rn(ci.z, cj.z);
        float d2 = __fadd_rn(__fadd_rn(__fmul_rn(dx, dx), __fmul_rn(dy, dy)),
                             __fmul_rn(dz, dz));
        d2 = __fadd_rn(d2, cj.w);
        keys[j] = (((ull)__float_as_uint(d2)) << 32) | (unsigned int)j;
    }
    __syncthreads();
    if (threadIdx.x >= 64) return;   // no further barriers: wave-synchronous

    const int l = threadIdx.x;
    const ull INF = ~0ull;
    ull m1 = INF, m2 = INF, m3 = INF;
#pragma unroll 8
    for (int q = 0; q < LEN / 64; ++q) ins3(keys[l + q * 64], m1, m2, m3);

    for (int k = 0; k < KNB; ++k) {
        ull r = m1;
#pragma unroll
        for (int off = 32; off >= 1; off >>= 1) {
            ull o = shfl_xor_u64(r, off);
            r = o < r ? o : r;
        }
        const unsigned int win = (unsigned int)(r & 0xFFFFFFFFull);
        if (l == 0) eidx_out[(size_t)row * KNB + k] = (float)win;
        if (m1 == r) {               // unique keys -> exactly one owner lane
            keys[win] = INF;         // win % 64 == l: zap own slot
            m1 = m2; m2 = m3; m3 = INF;
            if (m1 == INF) {         // cache exhausted: rescan own 32 slots
                for (int q = 0; q < LEN / 64; ++q) ins3(keys[l + q * 64], m1, m2, m3);
            }
        }
    }
}

// ---------------------------------------------------------------------------
// Kernel 2: edge features (bf16) + MFMA GEMM (32x416 @ 416x128) + LayerNorm.
// One block (256 thr, 4 waves) per (b,i). featE [32][424] bf16 (stride 848B ->
// 2-way-only bank aliasing). W chunk-staged [128][72] bf16. Wave w owns
// edges (w&1)*16..+16 x outputs (w>>1)*64..+64 = 4 MFMA tiles, K=416.
// ---------------------------------------------------------------------------
__device__ __forceinline__ void load_res_atoms(const float* __restrict__ p, float* dst) {
    const float Nx = p[0], Ny = p[1], Nz = p[2];
    const float Ax = p[3], Ay = p[4], Az = p[5];
    const float Cx = p[6], Cy = p[7], Cz = p[8];
    const float Ox = p[9], Oy = p[10], Oz = p[11];
    const float bx = Ax - Nx, by = Ay - Ny, bz = Az - Nz;
    const float cx = Cx - Ax, cy = Cy - Ay, cz = Cz - Az;
    const float axv = by * cz - bz * cy;
    const float ayv = bz * cx - bx * cz;
    const float azv = bx * cy - by * cx;
    dst[0] = Nx;  dst[1] = Ny;  dst[2] = Nz;
    dst[3] = Ax;  dst[4] = Ay;  dst[5] = Az;
    dst[6] = Cx;  dst[7] = Cy;  dst[8] = Cz;
    dst[9] = Ox;  dst[10] = Oy; dst[11] = Oz;
    dst[12] = -0.58273431f * axv + 0.56802827f * bx + -0.54067466f * cx + Ax;
    dst[13] = -0.58273431f * ayv + 0.56802827f * by + -0.54067466f * cy + Ay;
    dst[14] = -0.58273431f * azv + 0.56802827f * bz + -0.54067466f * cz + Az;
}

#define FSTRIDE 424   // bf16 elems; 848 B = 53*16B aligned, 212 dw % 32 = 20
#define WSTRIDE 72    // bf16 elems; 144 B = 9*16B aligned,  36 dw % 32 = 4

__global__ __launch_bounds__(256) void edge_kernel(
    const float* __restrict__ X,
    const int* __restrict__ Ridx, const int* __restrict__ Chain,
    const float* __restrict__ W_pos, const float* __restrict__ b_pos,
    const __bf16* __restrict__ Wbf,
    const float* __restrict__ lng, const float* __restrict__ lnb,
    const float* __restrict__ eidx_f, float* __restrict__ outE) {
    const int row = blockIdx.x;
    const int b = row >> 11;
    const int i = row & (LEN - 1);
    const int tid = threadIdx.x;

    __shared__ __align__(16) __bf16 featE[32 * FSTRIDE];  // 27136 B; reused as hbuf
    __shared__ __align__(16) __bf16 wc[128 * WSTRIDE];    // 18432 B
    __shared__ float natoms[32 * 16];
    __shared__ float iatoms[16];
    __shared__ int jidx[KNB];

    const float* Xb = X + (size_t)b * LEN * 12;

    if (tid < KNB) {
        const int j = (int)eidx_f[(size_t)row * KNB + tid];
        jidx[tid] = j;
        load_res_atoms(Xb + j * 12, natoms + tid * 16);
    } else if (tid == KNB) {
        load_res_atoms(Xb + i * 12, iatoms);
    }
    __syncthreads();

    // --- positional features -> featE[e][p], p=0..15
    const int Ri = Ridx[b * LEN + i];
    const int Ci = Chain[b * LEN + i];
#pragma unroll
    for (int it = 0; it < 2; ++it) {
        const int task = tid + it * 256;        // 512 = 32e x 16p
        const int e = task >> 4, p = task & 15;
        const int j = jidx[e];
        const int drel = Ridx[b * LEN + j] - Ri;
        const int same = (Chain[b * LEN + j] == Ci);
        int dc = drel + 32;
        dc = dc < 0 ? 0 : (dc > 64 ? 64 : dc);
        const int df = same ? dc : 65;
        featE[e * FSTRIDE + p] = (__bf16)(W_pos[p * 66 + df] + b_pos[p]);
    }

    // --- RBF features -> featE[e][16 + mn*16 + r]; packed 16B stores
    for (int task = tid; task < 800; task += 256) {
        const int mn = task >> 5, e = task & 31;
        const int m = mn / 5, n = mn - m * 5;
        const float ax = iatoms[m * 3 + 0];
        const float ay = iatoms[m * 3 + 1];
        const float az = iatoms[m * 3 + 2];
        const float* na = natoms + e * 16 + n * 3;
        const float dx = ax - na[0], dy = ay - na[1], dz = az - na[2];
        const float D = sqrtf(dx * dx + dy * dy + dz * dz + 1e-6f);
        bf16x8 v0, v1;
#pragma unroll
        for (int r = 0; r < 8; ++r) {
            const float mu = (float)(2.0 + (double)r * (20.0 / 15.0));
            const float t = D - mu;
            v0[r] = (__bf16)__expf(-(t * t) * (1.0f / 1.5625f));
        }
#pragma unroll
        for (int r = 8; r < 16; ++r) {
            const float mu = (float)(2.0 + (double)r * (20.0 / 15.0));
            const float t = D - mu;
            v1[r - 8] = (__bf16)__expf(-(t * t) * (1.0f / 1.5625f));
        }
        *(bf16x8*)(featE + e * FSTRIDE + 16 + mn * 16)     = v0;
        *(bf16x8*)(featE + e * FSTRIDE + 16 + mn * 16 + 8) = v1;
    }
    __syncthreads();

    // --- MFMA GEMM: h[e][t] = sum_k feat[e][k] * W[t][k]
    const int l  = tid & 63, w = tid >> 6;
    const int mt = w & 1;              // edge tile (16 edges)
    const int ntb = (w >> 1) * 4;      // first of 4 output tiles
    const int lr = l & 15, lg = l >> 4;

    f32x4 acc0 = {0.f, 0.f, 0.f, 0.f}, acc1 = acc0, acc2 = acc0, acc3 = acc0;

    for (int c = 0; c < 7; ++c) {
        const int kc = c * 64;
        // stage W chunk [128 t][<=64 k] bf16, 16B copies
        if (c < 6) {
            for (int q = tid; q < 1024; q += 256) {
                const int rrow = q >> 3, seg = q & 7;
                *(bf16x8*)(wc + rrow * WSTRIDE + seg * 8) =
                    *(const bf16x8*)(Wbf + rrow * 416 + kc + seg * 8);
            }
        } else {
            for (int q = tid; q < 512; q += 256) {
                const int rrow = q >> 2, seg = q & 3;
                *(bf16x8*)(wc + rrow * WSTRIDE + seg * 8) =
                    *(const bf16x8*)(Wbf + rrow * 416 + kc + seg * 8);
            }
        }
        __syncthreads();
        const int nks = (c == 6) ? 1 : 2;
        for (int ks = 0; ks < nks; ++ks) {
            const bf16x8 a = *(const bf16x8*)(featE + (mt * 16 + lr) * FSTRIDE
                                              + kc + ks * 32 + lg * 8);
            const __bf16* wbase = wc + lr * WSTRIDE + ks * 32 + lg * 8;
            bf16x8 b0 = *(const bf16x8*)(wbase + (ntb + 0) * 16 * WSTRIDE);
            bf16x8 b1 = *(const bf16x8*)(wbase + (ntb + 1) * 16 * WSTRIDE);
            bf16x8 b2 = *(const bf16x8*)(wbase + (ntb + 2) * 16 * WSTRIDE);
            bf16x8 b3 = *(const bf16x8*)(wbase + (ntb + 3) * 16 * WSTRIDE);
            acc0 = __builtin_amdgcn_mfma_f32_16x16x32_bf16(a, b0, acc0, 0, 0, 0);
            acc1 = __builtin_amdgcn_mfma_f32_16x16x32_bf16(a, b1, acc1, 0, 0, 0);
            acc2 = __builtin_amdgcn_mfma_f32_16x16x32_bf16(a, b2, acc2, 0, 0, 0);
            acc3 = __builtin_amdgcn_mfma_f32_16x16x32_bf16(a, b3, acc3, 0, 0, 0);
        }
        __syncthreads();
    }

    // --- scatter h to LDS (reuse featE as float hbuf[32][132])
    float* hbuf = (float*)featE;
    {
        const int e0 = mt * 16 + lg * 4;
#pragma unroll
        for (int r = 0; r < 4; ++r) {
            hbuf[(e0 + r) * 132 + (ntb + 0) * 16 + lr] = acc0[r];
            hbuf[(e0 + r) * 132 + (ntb + 1) * 16 + lr] = acc1[r];
            hbuf[(e0 + r) * 132 + (ntb + 2) * 16 + lr] = acc2[r];
            hbuf[(e0 + r) * 132 + (ntb + 3) * 16 + lr] = acc3[r];
        }
    }
    __syncthreads();

    // --- LayerNorm: 8 threads per edge, 16 values each
    const int g = tid >> 3, l2 = tid & 7;
    const float4* hb4 = (const float4*)(hbuf + g * 132 + l2 * 16);
    float4 vv[4];
    float s = 0.0f, ssq = 0.0f;
#pragma unroll
    for (int u = 0; u < 4; ++u) {
        vv[u] = hb4[u];
        s += vv[u].x + vv[u].y + vv[u].z + vv[u].w;
        ssq += vv[u].x * vv[u].x + vv[u].y * vv[u].y + vv[u].z * vv[u].z + vv[u].w * vv[u].w;
    }
#pragma unroll
    for (int off = 1; off < 8; off <<= 1) {
        s += __shfl_xor(s, off, 64);
        ssq += __shfl_xor(ssq, off, 64);
    }
    const float mean = s * (1.0f / 128.0f);
    const float rstd = rsqrtf(ssq * (1.0f / 128.0f) - mean * mean + 1e-5f);

    float4* ob = (float4*)(outE + ((size_t)row * KNB + g) * HID + l2 * 16);
    const float4* g4 = (const float4*)(lng + l2 * 16);
    const float4* b4 = (const float4*)(lnb + l2 * 16);
#pragma unroll
    for (int u = 0; u < 4; ++u) {
        const float4 gg = g4[u];
        const float4 bb = b4[u];
        float4 o;
        o.x = (vv[u].x - mean) * rstd * gg.x + bb.x;
        o.y = (vv[u].y - mean) * rstd * gg.y + bb.y;
        o.z = (vv[u].z - mean) * rstd * gg.z + bb.z;
        o.w = (vv[u].w - mean) * rstd * gg.w + bb.w;
        ob[u] = o;
    }
}

extern "C" void kernel_launch(void* const* d_in, const int* in_sizes, int n_in,
                              void* d_out, int out_size, void* d_ws, size_t ws_size,
                              hipStream_t stream) {
    const float* X      = (const float*)d_in[0];
    const float* mask   = (const float*)d_in[1];
    const int*   Ridx   = (const int*)d_in[2];
    const int*   Chain  = (const int*)d_in[3];
    const float* W_pos  = (const float*)d_in[4];
    const float* b_pos  = (const float*)d_in[5];
    const float* W_edge = (const float*)d_in[6];
    const float* lng    = (const float*)d_in[7];
    const float* lnb    = (const float*)d_in[8];

    float* out  = (float*)d_out;
    float* eidx = out;                           // B*L*K floats (exact ints)
    float* E    = out + (size_t)2 * LEN * KNB;   // B*L*K*HID floats

    float4* CAm = (float4*)d_ws;                          // 64 KiB
    __bf16* Wbf = (__bf16*)((char*)d_ws + 2 * LEN * 16);  // 104 KiB

    const int nrow = 2 * LEN;
    prep_kernel<<<208, 256, 0, stream>>>(X, mask, W_edge, CAm, Wbf);
    topk_kernel<<<nrow, 256, 0, stream>>>(CAm, eidx);
    edge_kernel<<<nrow, 256, 0, stream>>>(X, Ridx, Chain, W_pos, b_pos, Wbf,
                                          lng, lnb, eidx, E);
}

// Round 3
// 100.084 us; speedup vs baseline: 3.1257x; 1.8721x over previous
//
#include <hip/hip_runtime.h>
#include <hip/hip_bf16.h>

#define LEN   2048
#define KNB   32
#define HID   128

typedef unsigned long long ull;
typedef unsigned int uint32;
typedef __bf16 bf16x8 __attribute__((ext_vector_type(8)));
typedef float  f32x4  __attribute__((ext_vector_type(4)));

// ---------------------------------------------------------------------------
// Kernel 0: prep — pack CA coords + mask penalty as float4, convert W to bf16.
// ---------------------------------------------------------------------------
__global__ __launch_bounds__(256) void prep_kernel(
    const float* __restrict__ X, const float* __restrict__ mask,
    const float* __restrict__ W_edge,
    float4* __restrict__ CAm, __bf16* __restrict__ Wbf) {
    const int t = blockIdx.x * 256 + threadIdx.x;
    if (t < 2 * LEN) {
        const float* p = X + (size_t)t * 12;
        CAm[t] = make_float4(p[3], p[4], p[5],
                             __fmul_rn(__fsub_rn(1.0f, mask[t]), 1000000.0f));
    }
    Wbf[t] = (__bf16)W_edge[t];
}

// ---------------------------------------------------------------------------
// Kernel 1: exact top-K=32 via histogram-select. Keys (d2bits<<32|j) unique;
// bucket = d2bits>>22 is a monotone prefix, so candidates (bucket <= B) are
// strictly smaller than all non-candidates -> rank among candidates == global
// rank. Scatter-store eidx[rank] directly; no serial extraction rounds.
// ---------------------------------------------------------------------------
__global__ __launch_bounds__(256) void topk_kernel(
    const float4* __restrict__ CAm, float* __restrict__ eidx_out) {
    const int row = blockIdx.x;
    const int b = row >> 11;
    const int i = row & (LEN - 1);
    const int tid = threadIdx.x;

    __shared__ int hist[512];
    __shared__ ull cand[LEN];      // worst-case safe (M <= LEN)
    __shared__ int candcnt;
    __shared__ int selB;

    const float4* C = CAm + (size_t)b * LEN;
    const float4 ci = C[i];

    // keys in registers, exact rn-op order (matches numpy reference)
    uint32 d2b[8];
#pragma unroll
    for (int q = 0; q < 8; ++q) {
        const float4 cj = C[q * 256 + tid];
        float dx = __fsub_rn(ci.x, cj.x);
        float dy = __fsub_rn(ci.y, cj.y);
        float dz = __fsub_rn(ci.z, cj.z);
        float d2 = __fadd_rn(__fadd_rn(__fmul_rn(dx, dx), __fmul_rn(dy, dy)),
                             __fmul_rn(dz, dz));
        d2 = __fadd_rn(d2, cj.w);
        d2b[q] = __float_as_uint(d2);
    }

    hist[tid] = 0; hist[tid + 256] = 0;
    if (tid == 0) candcnt = 0;
    __syncthreads();
#pragma unroll
    for (int q = 0; q < 8; ++q) atomicAdd(&hist[d2b[q] >> 22], 1);
    __syncthreads();

    // one wave: find minimal bucket B with cumulative count >= 32
    if (tid < 64) {
        int loc[8];
        int s = 0;
#pragma unroll
        for (int t = 0; t < 8; ++t) { loc[t] = hist[tid * 8 + t]; s += loc[t]; }
        int incl = s;
#pragma unroll
        for (int off = 1; off < 64; off <<= 1) {
            int o = __shfl_up(incl, off, 64);
            if (tid >= off) incl += o;
        }
        const int excl = incl - s;
        if (excl < KNB && incl >= KNB) {   // exactly one lane
            int c = excl;
#pragma unroll
            for (int t = 0; t < 8; ++t) {
                int c2 = c + loc[t];
                if (c < KNB && c2 >= KNB) selB = tid * 8 + t;
                c = c2;
            }
        }
    }
    __syncthreads();
    const uint32 B = (uint32)selB;

    // compact candidates
#pragma unroll
    for (int q = 0; q < 8; ++q) {
        if ((d2b[q] >> 22) <= B) {
            int p = atomicAdd(&candcnt, 1);
            cand[p] = (((ull)d2b[q]) << 32) | (uint32)(q * 256 + tid);
        }
    }
    __syncthreads();
    const int M = candcnt;

    // rank each candidate among candidates (broadcast reads, conflict-free)
    for (int c = tid; c < M; c += 256) {
        const ull k = cand[c];
        int r = 0;
        for (int m = 0; m < M; ++m) r += (cand[m] < k);
        if (r < KNB)
            eidx_out[(size_t)row * KNB + r] = (float)(uint32)(k & 0xFFFFFFFFull);
    }
}

// ---------------------------------------------------------------------------
// Kernel 2: edge features (bf16) + MFMA GEMM (32x416 @ 416x128) + LayerNorm.
// One block (4 waves) per (b,i). featE [32][424] bf16 in LDS; W fragments
// loaded per-MFMA straight from global (L2-resident) -> no W staging, no
// K-loop barriers, ~30 KB LDS (5 blocks/CU).
// ---------------------------------------------------------------------------
__device__ __forceinline__ void load_res_atoms(const float* __restrict__ p, float* dst) {
    const float Nx = p[0], Ny = p[1], Nz = p[2];
    const float Ax = p[3], Ay = p[4], Az = p[5];
    const float Cx = p[6], Cy = p[7], Cz = p[8];
    const float Ox = p[9], Oy = p[10], Oz = p[11];
    const float bx = Ax - Nx, by = Ay - Ny, bz = Az - Nz;
    const float cx = Cx - Ax, cy = Cy - Ay, cz = Cz - Az;
    const float axv = by * cz - bz * cy;
    const float ayv = bz * cx - bx * cz;
    const float azv = bx * cy - by * cx;
    dst[0] = Nx;  dst[1] = Ny;  dst[2] = Nz;
    dst[3] = Ax;  dst[4] = Ay;  dst[5] = Az;
    dst[6] = Cx;  dst[7] = Cy;  dst[8] = Cz;
    dst[9] = Ox;  dst[10] = Oy; dst[11] = Oz;
    dst[12] = -0.58273431f * axv + 0.56802827f * bx + -0.54067466f * cx + Ax;
    dst[13] = -0.58273431f * ayv + 0.56802827f * by + -0.54067466f * cy + Ay;
    dst[14] = -0.58273431f * azv + 0.56802827f * bz + -0.54067466f * cz + Az;
}

#define FSTRIDE 424   // bf16; 848 B rows -> uniform granule spread for b128
#define NSTRIDE 17    // natoms float stride (kills 16-way conflict)

__global__ __launch_bounds__(256, 4) void edge_kernel(
    const float* __restrict__ X,
    const int* __restrict__ Ridx, const int* __restrict__ Chain,
    const float* __restrict__ W_pos, const float* __restrict__ b_pos,
    const __bf16* __restrict__ Wbf,
    const float* __restrict__ lng, const float* __restrict__ lnb,
    const float* __restrict__ eidx_f, float* __restrict__ outE) {
    const int row = blockIdx.x;
    const int b = row >> 11;
    const int i = row & (LEN - 1);
    const int tid = threadIdx.x;

    __shared__ __align__(16) __bf16 featE[32 * FSTRIDE];  // 27136 B; reused as hbuf
    __shared__ float natoms[32 * NSTRIDE];
    __shared__ float iatoms[16];
    __shared__ int jR[KNB], jC[KNB];

    const float* Xb = X + (size_t)b * LEN * 12;

    if (tid < KNB) {
        const int j = (int)eidx_f[(size_t)row * KNB + tid];
        jR[tid] = Ridx[b * LEN + j];
        jC[tid] = Chain[b * LEN + j];
        load_res_atoms(Xb + j * 12, natoms + tid * NSTRIDE);
    } else if (tid == KNB) {
        load_res_atoms(Xb + i * 12, iatoms);
    }
    __syncthreads();

    // --- positional features -> featE[e][p], p=0..15
    const int Ri = Ridx[b * LEN + i];
    const int Ci = Chain[b * LEN + i];
#pragma unroll
    for (int it = 0; it < 2; ++it) {
        const int task = tid + it * 256;        // 512 = 32e x 16p
        const int e = task >> 4, p = task & 15;
        const int drel = jR[e] - Ri;
        const int same = (jC[e] == Ci);
        int dc = drel + 32;
        dc = dc < 0 ? 0 : (dc > 64 ? 64 : dc);
        const int df = same ? dc : 65;
        featE[e * FSTRIDE + p] = (__bf16)(W_pos[p * 66 + df] + b_pos[p]);
    }

    // --- RBF features -> featE[e][16 + mn*16 + r]
    for (int task = tid; task < 800; task += 256) {
        const int mn = task >> 5, e = task & 31;
        const int m = mn / 5, n = mn - m * 5;
        const float ax = iatoms[m * 3 + 0];
        const float ay = iatoms[m * 3 + 1];
        const float az = iatoms[m * 3 + 2];
        const float* na = natoms + e * NSTRIDE + n * 3;
        const float dx = ax - na[0], dy = ay - na[1], dz = az - na[2];
        const float D = sqrtf(dx * dx + dy * dy + dz * dz + 1e-6f);
        bf16x8 v0, v1;
#pragma unroll
        for (int r = 0; r < 8; ++r) {
            const float mu = (float)(2.0 + (double)r * (20.0 / 15.0));
            const float t = D - mu;
            v0[r] = (__bf16)__expf(-(t * t) * (1.0f / 1.5625f));
        }
#pragma unroll
        for (int r = 8; r < 16; ++r) {
            const float mu = (float)(2.0 + (double)r * (20.0 / 15.0));
            const float t = D - mu;
            v1[r - 8] = (__bf16)__expf(-(t * t) * (1.0f / 1.5625f));
        }
        *(bf16x8*)(featE + e * FSTRIDE + 16 + mn * 16)     = v0;
        *(bf16x8*)(featE + e * FSTRIDE + 16 + mn * 16 + 8) = v1;
    }
    __syncthreads();

    // --- MFMA GEMM, B-fragments straight from global (L2-hit), no barriers
    const int l  = tid & 63, w = tid >> 6;
    const int mt = w & 1;              // edge tile (16 edges)
    const int ntb = (w >> 1) * 4;      // first of 4 output tiles
    const int lr = l & 15, lg = l >> 4;

    f32x4 acc0 = {0.f, 0.f, 0.f, 0.f}, acc1 = acc0, acc2 = acc0, acc3 = acc0;
    const __bf16* wb = Wbf + (size_t)(ntb * 16 + lr) * 416 + lg * 8;
    const __bf16* fb = featE + (mt * 16 + lr) * FSTRIDE + lg * 8;

#pragma unroll
    for (int ks = 0; ks < 13; ++ks) {
        const bf16x8 a  = *(const bf16x8*)(fb + ks * 32);
        const bf16x8 b0 = *(const bf16x8*)(wb + ks * 32);
        const bf16x8 b1 = *(const bf16x8*)(wb + 16 * 416 + ks * 32);
        const bf16x8 b2 = *(const bf16x8*)(wb + 32 * 416 + ks * 32);
        const bf16x8 b3 = *(const bf16x8*)(wb + 48 * 416 + ks * 32);
        acc0 = __builtin_amdgcn_mfma_f32_16x16x32_bf16(a, b0, acc0, 0, 0, 0);
        acc1 = __builtin_amdgcn_mfma_f32_16x16x32_bf16(a, b1, acc1, 0, 0, 0);
        acc2 = __builtin_amdgcn_mfma_f32_16x16x32_bf16(a, b2, acc2, 0, 0, 0);
        acc3 = __builtin_amdgcn_mfma_f32_16x16x32_bf16(a, b3, acc3, 0, 0, 0);
    }
    __syncthreads();   // all waves done reading featE

    // --- scatter h to LDS (reuse featE as float hbuf[32][132])
    float* hbuf = (float*)featE;
    {
        const int e0 = mt * 16 + lg * 4;
#pragma unroll
        for (int r = 0; r < 4; ++r) {
            hbuf[(e0 + r) * 132 + (ntb + 0) * 16 + lr] = acc0[r];
            hbuf[(e0 + r) * 132 + (ntb + 1) * 16 + lr] = acc1[r];
            hbuf[(e0 + r) * 132 + (ntb + 2) * 16 + lr] = acc2[r];
            hbuf[(e0 + r) * 132 + (ntb + 3) * 16 + lr] = acc3[r];
        }
    }
    __syncthreads();

    // --- LayerNorm: 8 threads per edge, 16 values each
    const int g = tid >> 3, l2 = tid & 7;
    const float4* hb4 = (const float4*)(hbuf + g * 132 + l2 * 16);
    float4 vv[4];
    float s = 0.0f, ssq = 0.0f;
#pragma unroll
    for (int u = 0; u < 4; ++u) {
        vv[u] = hb4[u];
        s += vv[u].x + vv[u].y + vv[u].z + vv[u].w;
        ssq += vv[u].x * vv[u].x + vv[u].y * vv[u].y + vv[u].z * vv[u].z + vv[u].w * vv[u].w;
    }
#pragma unroll
    for (int off = 1; off < 8; off <<= 1) {
        s += __shfl_xor(s, off, 64);
        ssq += __shfl_xor(ssq, off, 64);
    }
    const float mean = s * (1.0f / 128.0f);
    const float rstd = rsqrtf(ssq * (1.0f / 128.0f) - mean * mean + 1e-5f);

    float4* ob = (float4*)(outE + ((size_t)row * KNB + g) * HID + l2 * 16);
    const float4* g4 = (const float4*)(lng + l2 * 16);
    const float4* b4 = (const float4*)(lnb + l2 * 16);
#pragma unroll
    for (int u = 0; u < 4; ++u) {
        const float4 gg = g4[u];
        const float4 bb = b4[u];
        float4 o;
        o.x = (vv[u].x - mean) * rstd * gg.x + bb.x;
        o.y = (vv[u].y - mean) * rstd * gg.y + bb.y;
        o.z = (vv[u].z - mean) * rstd * gg.z + bb.z;
        o.w = (vv[u].w - mean) * rstd * gg.w + bb.w;
        ob[u] = o;
    }
}

extern "C" void kernel_launch(void* const* d_in, const int* in_sizes, int n_in,
                              void* d_out, int out_size, void* d_ws, size_t ws_size,
                              hipStream_t stream) {
    const float* X      = (const float*)d_in[0];
    const float* mask   = (const float*)d_in[1];
    const int*   Ridx   = (const int*)d_in[2];
    const int*   Chain  = (const int*)d_in[3];
    const float* W_pos  = (const float*)d_in[4];
    const float* b_pos  = (const float*)d_in[5];
    const float* W_edge = (const float*)d_in[6];
    const float* lng    = (const float*)d_in[7];
    const float* lnb    = (const float*)d_in[8];

    float* out  = (float*)d_out;
    float* eidx = out;                           // B*L*K floats (exact ints)
    float* E    = out + (size_t)2 * LEN * KNB;   // B*L*K*HID floats

    float4* CAm = (float4*)d_ws;                          // 64 KiB
    __bf16* Wbf = (__bf16*)((char*)d_ws + 2 * LEN * 16);  // 104 KiB

    const int nrow = 2 * LEN;
    prep_kernel<<<208, 256, 0, stream>>>(X, mask, W_edge, CAm, Wbf);
    topk_kernel<<<nrow, 256, 0, stream>>>(CAm, eidx);
    edge_kernel<<<nrow, 256, 0, stream>>>(X, Ridx, Chain, W_pos, b_pos, Wbf,
                                          lng, lnb, eidx, E);
}

// Round 4
// 63.938 us; speedup vs baseline: 4.8927x; 1.5653x over previous
//
#include <hip/hip_runtime.h>
#include <hip/hip_bf16.h>

#define LEN   2048
#define KNB   32
#define HID   128

typedef unsigned long long ull;
typedef unsigned int uint32;
typedef __bf16 bf16x8 __attribute__((ext_vector_type(8)));
typedef float  f32x4  __attribute__((ext_vector_type(4)));

// ---------------------------------------------------------------------------
// Kernel 0: prep — pack CA coords + mask penalty as float4, convert W to bf16.
// ---------------------------------------------------------------------------
__global__ __launch_bounds__(256) void prep_kernel(
    const float* __restrict__ X, const float* __restrict__ mask,
    const float* __restrict__ W_edge,
    float4* __restrict__ CAm, __bf16* __restrict__ Wbf) {
    const int t = blockIdx.x * 256 + threadIdx.x;
    if (t < 2 * LEN) {
        const float* p = X + (size_t)t * 12;
        CAm[t] = make_float4(p[3], p[4], p[5],
                             __fmul_rn(__fsub_rn(1.0f, mask[t]), 1000000.0f));
    }
    Wbf[t] = (__bf16)W_edge[t];
}

// ---------------------------------------------------------------------------
// Kernel 1: exact top-K=32 via histogram-select (unchanged from round 2).
// ---------------------------------------------------------------------------
__global__ __launch_bounds__(256) void topk_kernel(
    const float4* __restrict__ CAm, float* __restrict__ eidx_out) {
    const int row = blockIdx.x;
    const int b = row >> 11;
    const int i = row & (LEN - 1);
    const int tid = threadIdx.x;

    __shared__ int hist[512];
    __shared__ ull cand[LEN];
    __shared__ int candcnt;
    __shared__ int selB;

    const float4* C = CAm + (size_t)b * LEN;
    const float4 ci = C[i];

    uint32 d2b[8];
#pragma unroll
    for (int q = 0; q < 8; ++q) {
        const float4 cj = C[q * 256 + tid];
        float dx = __fsub_rn(ci.x, cj.x);
        float dy = __fsub_rn(ci.y, cj.y);
        float dz = __fsub_rn(ci.z, cj.z);
        float d2 = __fadd_rn(__fadd_rn(__fmul_rn(dx, dx), __fmul_rn(dy, dy)),
                             __fmul_rn(dz, dz));
        d2 = __fadd_rn(d2, cj.w);
        d2b[q] = __float_as_uint(d2);
    }

    hist[tid] = 0; hist[tid + 256] = 0;
    if (tid == 0) candcnt = 0;
    __syncthreads();
#pragma unroll
    for (int q = 0; q < 8; ++q) atomicAdd(&hist[d2b[q] >> 22], 1);
    __syncthreads();

    if (tid < 64) {
        int loc[8];
        int s = 0;
#pragma unroll
        for (int t = 0; t < 8; ++t) { loc[t] = hist[tid * 8 + t]; s += loc[t]; }
        int incl = s;
#pragma unroll
        for (int off = 1; off < 64; off <<= 1) {
            int o = __shfl_up(incl, off, 64);
            if (tid >= off) incl += o;
        }
        const int excl = incl - s;
        if (excl < KNB && incl >= KNB) {
            int c = excl;
#pragma unroll
            for (int t = 0; t < 8; ++t) {
                int c2 = c + loc[t];
                if (c < KNB && c2 >= KNB) selB = tid * 8 + t;
                c = c2;
            }
        }
    }
    __syncthreads();
    const uint32 B = (uint32)selB;

#pragma unroll
    for (int q = 0; q < 8; ++q) {
        if ((d2b[q] >> 22) <= B) {
            int p = atomicAdd(&candcnt, 1);
            cand[p] = (((ull)d2b[q]) << 32) | (uint32)(q * 256 + tid);
        }
    }
    __syncthreads();
    const int M = candcnt;

    for (int c = tid; c < M; c += 256) {
        const ull k = cand[c];
        int r = 0;
        for (int m = 0; m < M; ++m) r += (cand[m] < k);
        if (r < KNB)
            eidx_out[(size_t)row * KNB + r] = (float)(uint32)(k & 0xFFFFFFFFull);
    }
}

// ---------------------------------------------------------------------------
// Kernel 2: 8 rows per block, 512 threads (8 waves). Wave w holds its W-slice
// (16 outputs x K=416 = 13 x bf16x8) register-resident for the whole block;
// W read from L2 exactly once per block. Per row: features -> 26 MFMA -> LN.
// All 8 rows' atom/index gathers hoisted to one block prologue.
// ---------------------------------------------------------------------------
__device__ __forceinline__ void load_res_atoms(const float* __restrict__ p, float* dst) {
    const float Nx = p[0], Ny = p[1], Nz = p[2];
    const float Ax = p[3], Ay = p[4], Az = p[5];
    const float Cx = p[6], Cy = p[7], Cz = p[8];
    const float Ox = p[9], Oy = p[10], Oz = p[11];
    const float bx = Ax - Nx, by = Ay - Ny, bz = Az - Nz;
    const float cx = Cx - Ax, cy = Cy - Ay, cz = Cz - Az;
    const float axv = by * cz - bz * cy;
    const float ayv = bz * cx - bx * cz;
    const float azv = bx * cy - by * cx;
    dst[0] = Nx;  dst[1] = Ny;  dst[2] = Nz;
    dst[3] = Ax;  dst[4] = Ay;  dst[5] = Az;
    dst[6] = Cx;  dst[7] = Cy;  dst[8] = Cz;
    dst[9] = Ox;  dst[10] = Oy; dst[11] = Oz;
    dst[12] = -0.58273431f * axv + 0.56802827f * bx + -0.54067466f * cx + Ax;
    dst[13] = -0.58273431f * ayv + 0.56802827f * by + -0.54067466f * cy + Ay;
    dst[14] = -0.58273431f * azv + 0.56802827f * bz + -0.54067466f * cz + Az;
}

#define FSTRIDE 424   // bf16; dw-stride 212 % 32 = 20 -> only 2-way aliasing

__global__ __launch_bounds__(512, 4) void edge_kernel(
    const float* __restrict__ X,
    const int* __restrict__ Ridx, const int* __restrict__ Chain,
    const float* __restrict__ W_pos, const float* __restrict__ b_pos,
    const __bf16* __restrict__ Wbf,
    const float* __restrict__ lng, const float* __restrict__ lnb,
    const float* __restrict__ eidx_f, float* __restrict__ outE) {
    const int tid = threadIdx.x;
    const int row0 = blockIdx.x * 8;
    const int b = row0 >> 11;                 // 2048 % 8 == 0: no batch straddle
    const int i0 = row0 & (LEN - 1);

    __shared__ __align__(16) __bf16 featE[32 * FSTRIDE];  // 27136 B
    __shared__ __align__(16) float hbuf[32 * 132];        // 16896 B
    __shared__ float natoms8[8][32][17];                  // 17408 B
    __shared__ float iatoms8[8][16];                      //   512 B
    __shared__ int jR8[8][32], jC8[8][32];                //  2048 B

    const float* Xb = X + (size_t)b * LEN * 12;

    // --- W register residency: wave w owns outputs w*16 + lr
    const int w = tid >> 6, l = tid & 63, lr = l & 15, lg = l >> 4;
    bf16x8 wreg[13];
    {
        const __bf16* wb = Wbf + (size_t)(w * 16 + lr) * 416 + lg * 8;
#pragma unroll
        for (int ks = 0; ks < 13; ++ks)
            wreg[ks] = *(const bf16x8*)(wb + ks * 32);
    }

    // --- prologue: all 8 rows' neighbor atoms + indices
    if (tid < 256) {
        const int r8 = tid >> 5, e = tid & 31;
        const int j = (int)eidx_f[(size_t)(row0 + r8) * KNB + e];
        jR8[r8][e] = Ridx[b * LEN + j];
        jC8[r8][e] = Chain[b * LEN + j];
        load_res_atoms(Xb + j * 12, &natoms8[r8][e][0]);
    } else if (tid < 264) {
        const int r8 = tid - 256;
        load_res_atoms(Xb + (size_t)(i0 + r8) * 12, &iatoms8[r8][0]);
    }
    __syncthreads();

    for (int r8 = 0; r8 < 8; ++r8) {
        const int row = row0 + r8;
        const int i = i0 + r8;
        const int Ri = Ridx[b * LEN + i];
        const int Ci = Chain[b * LEN + i];

        // --- positional features: 512 tasks = 32e x 16p
        {
            const int e = tid >> 4, p = tid & 15;
            const int drel = jR8[r8][e] - Ri;
            const int same = (jC8[r8][e] == Ci);
            int dc = drel + 32;
            dc = dc < 0 ? 0 : (dc > 64 ? 64 : dc);
            const int df = same ? dc : 65;
            featE[e * FSTRIDE + p] = (__bf16)(W_pos[p * 66 + df] + b_pos[p]);
        }
        // --- RBF features: 800 tasks over 512 threads
#pragma unroll
        for (int it = 0; it < 2; ++it) {
            const int task = tid + it * 512;
            if (task < 800) {
                const int mn = task >> 5, e = task & 31;
                const int m = mn / 5, n = mn - m * 5;
                const float ax = iatoms8[r8][m * 3 + 0];
                const float ay = iatoms8[r8][m * 3 + 1];
                const float az = iatoms8[r8][m * 3 + 2];
                const float* na = &natoms8[r8][e][n * 3];
                const float dx = ax - na[0], dy = ay - na[1], dz = az - na[2];
                const float D = sqrtf(dx * dx + dy * dy + dz * dz + 1e-6f);
                bf16x8 v0, v1;
#pragma unroll
                for (int r = 0; r < 8; ++r) {
                    const float mu = (float)(2.0 + (double)r * (20.0 / 15.0));
                    const float t = D - mu;
                    v0[r] = (__bf16)__expf(-(t * t) * (1.0f / 1.5625f));
                }
#pragma unroll
                for (int r = 8; r < 16; ++r) {
                    const float mu = (float)(2.0 + (double)r * (20.0 / 15.0));
                    const float t = D - mu;
                    v1[r - 8] = (__bf16)__expf(-(t * t) * (1.0f / 1.5625f));
                }
                *(bf16x8*)(featE + e * FSTRIDE + 16 + mn * 16)     = v0;
                *(bf16x8*)(featE + e * FSTRIDE + 16 + mn * 16 + 8) = v1;
            }
        }
        __syncthreads();

        // --- GEMM: 2 edge-tiles x 13 K-steps, B from registers
        f32x4 acc0 = {0.f, 0.f, 0.f, 0.f}, acc1 = acc0;
        const __bf16* fb0 = featE + lr * FSTRIDE + lg * 8;
        const __bf16* fb1 = featE + (16 + lr) * FSTRIDE + lg * 8;
#pragma unroll
        for (int ks = 0; ks < 13; ++ks) {
            const bf16x8 a0 = *(const bf16x8*)(fb0 + ks * 32);
            const bf16x8 a1 = *(const bf16x8*)(fb1 + ks * 32);
            acc0 = __builtin_amdgcn_mfma_f32_16x16x32_bf16(a0, wreg[ks], acc0, 0, 0, 0);
            acc1 = __builtin_amdgcn_mfma_f32_16x16x32_bf16(a1, wreg[ks], acc1, 0, 0, 0);
        }
        // scatter h (C/D layout: col = lr = output, row = lg*4+rr = edge)
#pragma unroll
        for (int rr = 0; rr < 4; ++rr) {
            hbuf[(lg * 4 + rr) * 132 + w * 16 + lr]        = acc0[rr];
            hbuf[(16 + lg * 4 + rr) * 132 + w * 16 + lr]   = acc1[rr];
        }
        __syncthreads();

        // --- LayerNorm: 16 threads per edge, 8 values each
        const int g = tid >> 4, l2 = tid & 15;
        const float4* hb4 = (const float4*)(hbuf + g * 132 + l2 * 8);
        const float4 v0 = hb4[0], v1 = hb4[1];
        float s = v0.x + v0.y + v0.z + v0.w + v1.x + v1.y + v1.z + v1.w;
        float ssq = v0.x * v0.x + v0.y * v0.y + v0.z * v0.z + v0.w * v0.w
                  + v1.x * v1.x + v1.y * v1.y + v1.z * v1.z + v1.w * v1.w;
#pragma unroll
        for (int off = 1; off < 16; off <<= 1) {
            s += __shfl_xor(s, off, 64);
            ssq += __shfl_xor(ssq, off, 64);
        }
        const float mean = s * (1.0f / 128.0f);
        const float rstd = rsqrtf(ssq * (1.0f / 128.0f) - mean * mean + 1e-5f);

        float4* ob = (float4*)(outE + ((size_t)row * KNB + g) * HID + l2 * 8);
        const float4 g0 = *(const float4*)(lng + l2 * 8);
        const float4 g1 = *(const float4*)(lng + l2 * 8 + 4);
        const float4 b0 = *(const float4*)(lnb + l2 * 8);
        const float4 b1 = *(const float4*)(lnb + l2 * 8 + 4);
        float4 o0, o1;
        o0.x = (v0.x - mean) * rstd * g0.x + b0.x;
        o0.y = (v0.y - mean) * rstd * g0.y + b0.y;
        o0.z = (v0.z - mean) * rstd * g0.z + b0.z;
        o0.w = (v0.w - mean) * rstd * g0.w + b0.w;
        o1.x = (v1.x - mean) * rstd * g1.x + b1.x;
        o1.y = (v1.y - mean) * rstd * g1.y + b1.y;
        o1.z = (v1.z - mean) * rstd * g1.z + b1.z;
        o1.w = (v1.w - mean) * rstd * g1.w + b1.w;
        ob[0] = o0;
        ob[1] = o1;
    }
}

extern "C" void kernel_launch(void* const* d_in, const int* in_sizes, int n_in,
                              void* d_out, int out_size, void* d_ws, size_t ws_size,
                              hipStream_t stream) {
    const float* X      = (const float*)d_in[0];
    const float* mask   = (const float*)d_in[1];
    const int*   Ridx   = (const int*)d_in[2];
    const int*   Chain  = (const int*)d_in[3];
    const float* W_pos  = (const float*)d_in[4];
    const float* b_pos  = (const float*)d_in[5];
    const float* W_edge = (const float*)d_in[6];
    const float* lng    = (const float*)d_in[7];
    const float* lnb    = (const float*)d_in[8];

    float* out  = (float*)d_out;
    float* eidx = out;                           // B*L*K floats (exact ints)
    float* E    = out + (size_t)2 * LEN * KNB;   // B*L*K*HID floats

    float4* CAm = (float4*)d_ws;                          // 64 KiB
    __bf16* Wbf = (__bf16*)((char*)d_ws + 2 * LEN * 16);  // 104 KiB

    const int nrow = 2 * LEN;
    prep_kernel<<<208, 256, 0, stream>>>(X, mask, W_edge, CAm, Wbf);
    topk_kernel<<<nrow, 256, 0, stream>>>(CAm, eidx);
    edge_kernel<<<nrow / 8, 512, 0, stream>>>(X, Ridx, Chain, W_pos, b_pos, Wbf,
                                              lng, lnb, eidx, E);
}